// Round 4
// baseline (290.885 us; speedup 1.0000x reference)
//
#include <hip/hip_runtime.h>

// Problem: adjacency_full[i, neighbor_indices[i,k]] = adjacency_values[i,k]
// over a zeroed [N,N] fp32 matrix. N=8192, K=64.
//
// v5: v2 structure (single dispatch, row-per-block, reg zero-stream + patch)
// with ALL stores NON-TEMPORAL.
//
// Evidence trail: v1 (LDS), v2 (reg-stream), v3 (fill-clone), v4 (rocclr's own
// fill via hipMemsetAsync) ALL run at ~2.7-2.9 TB/s on this 256 MiB output,
// while the identical rocclr fill writes the 1 GiB poison buffer at 6.4 TB/s
// in the same capture. Difference: the poison fill MISSES in the 256 MiB L3
// (4x footprint, streaming path -> HBM at 6.4); our output's lines are
// L3-RESIDENT (the poison fill wrote them last), so our stores take the
// write-HIT update path at ~2.9 TB/s. Kernel structure is exonerated four ways.
// Lever: `nt` stores request the no-allocate/streaming path regardless of
// residency. nt affects allocation policy only, not coherency: the
// vmcnt(0)-drain in __syncthreads() still orders zero-stream vs patch, and
// same-stream ordering covers inter-phase visibility.

constexpr int N_PATCH = 8192;
constexpr int K_NB = 64;
constexpr int BLOCK = 256;
constexpr int VEC_ITERS = N_PATCH / 4 / BLOCK;  // 8 x 16B per thread

typedef float f32x4 __attribute__((ext_vector_type(4)));

__global__ __launch_bounds__(BLOCK)
void scatter_rows_kernel(const float* __restrict__ vals,
                         const int* __restrict__ idx,
                         float* __restrict__ out) {
    const int r = blockIdx.x;
    const int t = threadIdx.x;

    // Prefetch this row's scatter pair early; HBM latency hides under stores.
    int c = 0;
    float v = 0.f;
    if (t < K_NB) {
        const int base = r * K_NB + t;
        c = idx[base];
        v = vals[base];
    }
    asm volatile("" : "+v"(c), "+v"(v));

    // Zero stream: fully coalesced 16 B non-temporal stores (no L3 allocate,
    // no write-hit update path -> streaming/miss path at HBM rate).
    f32x4* outv = reinterpret_cast<f32x4*>(out + (size_t)r * N_PATCH);
    const f32x4 z = {0.f, 0.f, 0.f, 0.f};
#pragma unroll
    for (int i = 0; i < VEC_ITERS; ++i)
        __builtin_nontemporal_store(z, &outv[t + i * BLOCK]);

    // Drain zero stores (vmcnt(0) precedes s_barrier), then patch.
    __syncthreads();

    // Scattered 4 B patches, also non-temporal (avoid 128 B write-allocate
    // fetches of lines we just streamed out).
    if (t < K_NB)
        __builtin_nontemporal_store(v, &out[(size_t)r * N_PATCH + c]);
}

extern "C" void kernel_launch(void* const* d_in, const int* in_sizes, int n_in,
                              void* d_out, int out_size, void* d_ws, size_t ws_size,
                              hipStream_t stream) {
    const float* vals = (const float*)d_in[0];   // adjacency_values [N,K] fp32
    const int* idx = (const int*)d_in[1];        // neighbor_indices [N,K] int32
    float* out = (float*)d_out;                  // [N,N] fp32

    scatter_rows_kernel<<<N_PATCH, BLOCK, 0, stream>>>(vals, idx, out);
}

// Round 5
// 268.988 us; speedup vs baseline: 1.0814x; 1.0814x over previous
//
#include <hip/hip_runtime.h>

// Problem: adjacency_full[i, neighbor_indices[i,k]] = adjacency_values[i,k]
// over a zeroed [N,N] fp32 matrix. N=8192, K=64.
//
// v6: v1 structure (build the complete row in LDS: zeros + scattered patches
// merged), then stream out with FULL-LINE-ONLY non-temporal stores.
//
// Evidence trail: v1 LDS-stage (99us), v2 reg-stream+patch (95us), v3
// fill-clone+scatter (108us), v4 rocclr-fill-via-memset+scatter (98us) all pin
// at ~2.7-2.9 TB/s on this 256 MiB output while the same rocclr fill does
// 6.4 TB/s on the 1 GiB poison buffer. v5 (nt everywhere) REGRESSED (+25us) —
// but it mixed full-line nt stream with 512K partial-line 4B nt stores, and a
// partial-line nt store forces an HBM-side RMW.
//
// Current theory: the poison fill leaves L3 full of dirty poison lines at
// OTHER addresses; our allocating stores evict a dirty victim per line ->
// our window pays ~512 MiB of HBM traffic (zeros + displaced poison) ~= the
// ~95us floor seen by every allocating variant including the vendor fill.
// This version emits ONLY full-line nt stores (patches pre-merged in LDS):
// if nt full-line stores stream without allocation, victim evictions vanish.

constexpr int N_PATCH = 8192;
constexpr int K_NB = 64;
constexpr int BLOCK = 256;
constexpr int VEC_ITERS = N_PATCH / 4 / BLOCK;  // 8 x 16B per thread

typedef float f32x4 __attribute__((ext_vector_type(4)));

__global__ __launch_bounds__(BLOCK)
void scatter_rows_kernel(const float* __restrict__ vals,
                         const int* __restrict__ idx,
                         float* __restrict__ out) {
    __shared__ float row[N_PATCH];  // 32 KiB
    const int r = blockIdx.x;
    const int t = threadIdx.x;

    // Prefetch this row's scatter pair while we zero the LDS row.
    int c = 0;
    float v = 0.f;
    if (t < K_NB) {
        const int base = r * K_NB + t;
        c = idx[base];
        v = vals[base];
    }

    // Zero the LDS row (16B/lane, conflict-free).
    f32x4* rowv = reinterpret_cast<f32x4*>(row);
    const f32x4 z = {0.f, 0.f, 0.f, 0.f};
#pragma unroll
    for (int i = 0; i < VEC_ITERS; ++i)
        rowv[t + i * BLOCK] = z;
    __syncthreads();

    // Merge the K=64 patches into the LDS row.
    if (t < K_NB)
        row[c] = v;
    __syncthreads();

    // Stream the finished row to global: ONLY full-line, coalesced,
    // non-temporal 16B stores (8 consecutive lanes cover one 128B line).
    f32x4* outv = reinterpret_cast<f32x4*>(out + (size_t)r * N_PATCH);
#pragma unroll
    for (int i = 0; i < VEC_ITERS; ++i)
        __builtin_nontemporal_store(rowv[t + i * BLOCK], &outv[t + i * BLOCK]);
}

extern "C" void kernel_launch(void* const* d_in, const int* in_sizes, int n_in,
                              void* d_out, int out_size, void* d_ws, size_t ws_size,
                              hipStream_t stream) {
    const float* vals = (const float*)d_in[0];   // adjacency_values [N,K] fp32
    const int* idx = (const int*)d_in[1];        // neighbor_indices [N,K] int32
    float* out = (float*)d_out;                  // [N,N] fp32

    scatter_rows_kernel<<<N_PATCH, BLOCK, 0, stream>>>(vals, idx, out);
}